// Round 3
// baseline (759.369 us; speedup 1.0000x reference)
//
#include <hip/hip_runtime.h>

// ---------------------------------------------------------------------------
// BiasCrossAttentionFusion on gfx950 — round 2.
//   R2 vs R1 (611us, flash 188us @ 23% occupancy):
//   * k_flash: KV-split across wave pairs (valid because no online max ->
//     o,l are plain sums), 64 Q-rows/block, grid 512->1024 = 4 blocks/CU,
//     __launch_bounds__(256,4); partials combined via LDS (aliases P buffer).
//   * V^T produced directly by the WV GEMM (operand swap, row-bias epilogue)
//     -> k_vtrans deleted.
//   * geo projections: single launch, 32-row tiles (384 blocks).
//   * l2norm: 2-phase coalesced; both norms folded into one geo_k scale.
//   * all transposes in 1 launch; both input LNs in 1 launch (19->14 dispatches)
// ---------------------------------------------------------------------------

typedef __bf16 bf16x8 __attribute__((ext_vector_type(8)));
typedef float  f32x4  __attribute__((ext_vector_type(4)));

__device__ inline f32x4 mfma16(bf16x8 a, bf16x8 b, f32x4 c) {
  return __builtin_amdgcn_mfma_f32_16x16x32_bf16(a, b, c, 0, 0, 0);
}

__device__ inline void glds16(const void* g, void* l) {
  __builtin_amdgcn_global_load_lds(
      (const __attribute__((address_space(1))) void*)g,
      (__attribute__((address_space(3))) void*)l, 16, 0, 0);
}

#define DB 1024
#define DH 16
#define DHD 64
#define DP 64
#define NB 4
#define NN 1024
#define NM 2048

// ---------------- all weight transposes (f32 [K,O] -> bf16 [O,K]) ----------
__global__ __launch_bounds__(256) void k_transpose_all(
    const float* __restrict__ w0, const float* __restrict__ w1,
    const float* __restrict__ w2, const float* __restrict__ w3,
    const float* __restrict__ f1, const float* __restrict__ f2,
    const float* __restrict__ g0, const float* __restrict__ g1,
    __bf16* __restrict__ o0, __bf16* __restrict__ o1,
    __bf16* __restrict__ o2, __bf16* __restrict__ o3,
    __bf16* __restrict__ of1, __bf16* __restrict__ of2,
    __bf16* __restrict__ og0, __bf16* __restrict__ og1) {
  __shared__ float tile[32][33];
  int id = blockIdx.x;
  const float* in;
  __bf16* out;
  int K, O, x, y;
  if (id < 4096) {
    int mi = id >> 10, r = id & 1023;
    in = mi == 0 ? w0 : mi == 1 ? w1 : mi == 2 ? w2 : w3;
    out = mi == 0 ? o0 : mi == 1 ? o1 : mi == 2 ? o2 : o3;
    K = 1024; O = 1024; x = r & 31; y = r >> 5;
  } else if (id < 6144) {
    int r = id - 4096; in = f1; out = of1; K = 1024; O = 2048; x = r & 63; y = r >> 6;
  } else if (id < 8192) {
    int r = id - 6144; in = f2; out = of2; K = 2048; O = 1024; x = r & 31; y = r >> 5;
  } else if (id < 8256) {
    int r = id - 8192; in = g0; out = og0; K = 1024; O = 64; x = r & 1; y = r >> 1;
  } else {
    int r = id - 8256; in = g1; out = og1; K = 1024; O = 64; x = r & 1; y = r >> 1;
  }
  int k0 = y * 32, o0c = x * 32;
  int tx = threadIdx.x & 31, ty = threadIdx.x >> 5;
#pragma unroll
  for (int r = ty; r < 32; r += 8)
    tile[r][tx] = in[(size_t)(k0 + r) * O + (o0c + tx)];
  __syncthreads();
#pragma unroll
  for (int r = ty; r < 32; r += 8)
    out[(size_t)(o0c + r) * K + (k0 + tx)] = (__bf16)tile[tx][r];
}

// ---------------- LayerNorm D=1024, one block/row, bf16 out ----------------
__device__ inline void ln_body(const float* __restrict__ x,
                               const float* __restrict__ g,
                               const float* __restrict__ bb,
                               __bf16* __restrict__ y, size_t row) {
  int t = threadIdx.x;
  float4 v = ((const float4*)(x + row * 1024))[t];
  float s = v.x + v.y + v.z + v.w;
  float ss = v.x * v.x + v.y * v.y + v.z * v.z + v.w * v.w;
#pragma unroll
  for (int o = 32; o; o >>= 1) {
    s += __shfl_down(s, o, 64);
    ss += __shfl_down(ss, o, 64);
  }
  __shared__ float r1[4], r2[4];
  if ((t & 63) == 0) { r1[t >> 6] = s; r2[t >> 6] = ss; }
  __syncthreads();
  s = r1[0] + r1[1] + r1[2] + r1[3];
  ss = r2[0] + r2[1] + r2[2] + r2[3];
  float mu = s * (1.f / 1024.f);
  float rstd = rsqrtf(ss * (1.f / 1024.f) - mu * mu + 1e-5f);
  float4 gv = ((const float4*)g)[t];
  float4 bv = ((const float4*)bb)[t];
  __bf16* yr = y + row * 1024 + t * 4;
  yr[0] = (__bf16)((v.x - mu) * rstd * gv.x + bv.x);
  yr[1] = (__bf16)((v.y - mu) * rstd * gv.y + bv.y);
  yr[2] = (__bf16)((v.z - mu) * rstd * gv.z + bv.z);
  yr[3] = (__bf16)((v.w - mu) * rstd * gv.w + bv.w);
}

__global__ __launch_bounds__(256) void k_layernorm(
    const float* __restrict__ x, const float* __restrict__ g,
    const float* __restrict__ bb, __bf16* __restrict__ y) {
  ln_body(x, g, bb, y, blockIdx.x);
}

__global__ __launch_bounds__(256) void k_layernorm2(
    const float* __restrict__ x1, const float* __restrict__ g1,
    const float* __restrict__ b1, __bf16* __restrict__ y1,
    const float* __restrict__ x2, const float* __restrict__ g2,
    const float* __restrict__ b2, __bf16* __restrict__ y2) {
  int row = blockIdx.x;
  if (row < 4096) ln_body(x1, g1, b1, y1, row);
  else ln_body(x2, g2, b2, y2, row - 4096);
}

// ---------------- geo projections: q(128 blk) + kv(256 blk), 32x64 tiles ---
__global__ __launch_bounds__(256) void k_geo(
    const __bf16* __restrict__ qin, const __bf16* __restrict__ kvin,
    const __bf16* __restrict__ gqw, const __bf16* __restrict__ gkw,
    const float* __restrict__ gqb, const float* __restrict__ gkb,
    __bf16* __restrict__ geoq, __bf16* __restrict__ geok) {
  const int blk = blockIdx.x;
  const bool isq = blk < 128;
  const __bf16* A = isq ? qin : kvin;
  const __bf16* Bt = isq ? gqw : gkw;
  const float* bias = isq ? gqb : gkb;
  __bf16* C = isq ? geoq : geok;
  const int row0 = (isq ? blk : blk - 128) * 32;
  __shared__ __align__(16) __bf16 As[32][72], Bs[64][72];
  const int t = threadIdx.x, lane = t & 63, w = t >> 6;
  const int quad = lane >> 4, l15 = lane & 15;
  const int wr = w >> 1, wc = w & 1;
  const int sr = t >> 3, skc = (t & 7) * 8;
  const __bf16* aP = A + (size_t)(row0 + sr) * 1024 + skc;
  const __bf16* bP0 = Bt + (size_t)sr * 1024 + skc;
  const __bf16* bP1 = Bt + (size_t)(sr + 32) * 1024 + skc;
  bf16x8 av = *(const bf16x8*)aP;
  bf16x8 bv0 = *(const bf16x8*)bP0;
  bf16x8 bv1 = *(const bf16x8*)bP1;
  f32x4 acc[2] = {};
  for (int k0 = 0; k0 < 1024; k0 += 64) {
    __syncthreads();
    *(bf16x8*)&As[sr][skc] = av;
    *(bf16x8*)&Bs[sr][skc] = bv0;
    *(bf16x8*)&Bs[sr + 32][skc] = bv1;
    __syncthreads();
    if (k0 + 64 < 1024) {
      av = *(const bf16x8*)(aP + k0 + 64);
      bv0 = *(const bf16x8*)(bP0 + k0 + 64);
      bv1 = *(const bf16x8*)(bP1 + k0 + 64);
    }
#pragma unroll
    for (int ks = 0; ks < 2; ks++) {
      bf16x8 af = *(const bf16x8*)&As[wr * 16 + l15][ks * 32 + quad * 8];
#pragma unroll
      for (int ct = 0; ct < 2; ct++) {
        bf16x8 bfr = *(const bf16x8*)&Bs[wc * 32 + ct * 16 + l15][ks * 32 + quad * 8];
        acc[ct] = mfma16(af, bfr, acc[ct]);
      }
    }
  }
#pragma unroll
  for (int ct = 0; ct < 2; ct++) {
    int col = wc * 32 + ct * 16 + l15;
    float bc = bias[col];
#pragma unroll
    for (int i = 0; i < 4; i++) {
      int row = row0 + wr * 16 + quad * 4 + i;
      C[(size_t)row * 64 + col] = (__bf16)(acc[ct][i] + bc);
    }
  }
}

// ---------------- l2 norms, phase 1: column sum-of-squares -----------------
// sums layout: [z(0=q,1=k)][b][64] f32
__global__ __launch_bounds__(256) void k_l2sum(
    const __bf16* __restrict__ gq, const __bf16* __restrict__ gk,
    float* __restrict__ sums) {
  int chunk = blockIdx.x, b = blockIdx.y, z = blockIdx.z;
  if (z == 0 && chunk >= 8) return;
  const __bf16* src = z ? gk : gq;
  int rows = z ? 2048 : 1024;
  const unsigned* base = (const unsigned*)(src + (size_t)b * rows * 64) + chunk * 128 * 32;
  int t = threadIdx.x, c = t & 31, ro = t >> 5;
  float s0 = 0.f, s1 = 0.f;
  for (int r = ro; r < 128; r += 8) {
    unsigned u = base[r * 32 + c];
    float f0 = __uint_as_float(u << 16);
    float f1 = __uint_as_float(u & 0xffff0000u);
    s0 += f0 * f0;
    s1 += f1 * f1;
  }
  __shared__ float ls[64];
  if (t < 64) ls[t] = 0.f;
  __syncthreads();
  atomicAdd(&ls[c * 2], s0);
  atomicAdd(&ls[c * 2 + 1], s1);
  __syncthreads();
  if (t < 64) atomicAdd(&sums[z * 256 + b * 64 + t], ls[t]);
}

// ---------------- l2 phase 2: scale geo_k by 1/(||q_p||*||k_p||) -----------
__global__ __launch_bounds__(256) void k_l2scale(
    __bf16* __restrict__ gk, const float* __restrict__ sums) {
  int chunk = blockIdx.x, b = blockIdx.y;
  unsigned* base = (unsigned*)(gk + (size_t)b * 2048 * 64) + chunk * 128 * 32;
  int t = threadIdx.x, c = t & 31, ro = t >> 5;
  float sq0 = sums[b * 64 + c * 2], sq1 = sums[b * 64 + c * 2 + 1];
  float sk0 = sums[256 + b * 64 + c * 2], sk1 = sums[256 + b * 64 + c * 2 + 1];
  float m0 = 1.f / (fmaxf(sqrtf(sq0), 1e-12f) * fmaxf(sqrtf(sk0), 1e-12f));
  float m1 = 1.f / (fmaxf(sqrtf(sq1), 1e-12f) * fmaxf(sqrtf(sk1), 1e-12f));
  for (int r = ro; r < 128; r += 8) {
    unsigned u = base[r * 32 + c];
    float f0 = __uint_as_float(u << 16) * m0;
    float f1 = __uint_as_float(u & 0xffff0000u) * m1;
    unsigned short h0 = __builtin_bit_cast(unsigned short, (__bf16)f0);
    unsigned short h1 = __builtin_bit_cast(unsigned short, (__bf16)f1);
    base[r * 32 + c] = (unsigned)h0 | ((unsigned)h1 << 16);
  }
}

// ---------------- big GEMM: m97 structure, 128x128 tile, global_load_lds ---
// EPI: 0 = +bias(col) -> bf16 | 2 = +bias(col) +residual -> f32
//      3 = +bias(col), exact gelu -> bf16 | 4 = +bias(row) -> bf16 (V^T)
template <int EPI>
__global__ __launch_bounds__(256, 2) void k_gemm128(
    const __bf16* __restrict__ A, const __bf16* __restrict__ Bt,
    const float* __restrict__ bias, const float* __restrict__ resid,
    void* __restrict__ Cout, int Mdim, int Ndim, int Kdim) {
  __shared__ __align__(16) __bf16 As[128 * 32];
  __shared__ __align__(16) __bf16 Bs[128 * 32];
  const int m0 = blockIdx.y * 128, n0 = blockIdx.x * 128;
  const int t = threadIdx.x, lane = t & 63, w = t >> 6;
  const int quad = lane >> 4, l15 = lane & 15;
  const int wr = w >> 1, wc = w & 1;
  const int srow = lane >> 2, scol = (lane & 3) * 8;
  const __bf16* aS0 = A + (size_t)(m0 + w * 32 + srow) * Kdim + scol;
  const __bf16* bS0 = Bt + (size_t)(n0 + w * 32 + srow) * Kdim + scol;
  const size_t K16 = (size_t)16 * Kdim;
  __bf16* lA0 = &As[(w * 32) * 32];
  __bf16* lB0 = &Bs[(w * 32) * 32];

  f32x4 acc[4][4] = {};
  for (int k0 = 0; k0 < Kdim; k0 += 32) {
    __syncthreads();
    glds16(aS0 + k0, lA0);
    glds16(aS0 + K16 + k0, lA0 + 16 * 32);
    glds16(bS0 + k0, lB0);
    glds16(bS0 + K16 + k0, lB0 + 16 * 32);
    __syncthreads();
    bf16x8 af[4], bg[4];
#pragma unroll
    for (int rt = 0; rt < 4; rt++)
      af[rt] = *(const bf16x8*)&As[(wr * 64 + rt * 16 + l15) * 32 + quad * 8];
#pragma unroll
    for (int ct = 0; ct < 4; ct++)
      bg[ct] = *(const bf16x8*)&Bs[(wc * 64 + ct * 16 + l15) * 32 + quad * 8];
#pragma unroll
    for (int rt = 0; rt < 4; rt++)
#pragma unroll
      for (int ct = 0; ct < 4; ct++)
        acc[rt][ct] = mfma16(af[rt], bg[ct], acc[rt][ct]);
  }
#pragma unroll
  for (int rt = 0; rt < 4; rt++) {
    int row = m0 + wr * 64 + rt * 16 + quad * 4;
#pragma unroll
    for (int ct = 0; ct < 4; ct++) {
      int col = n0 + wc * 64 + ct * 16 + l15;
      float bcol = (EPI == 4) ? 0.f : bias[col];
#pragma unroll
      for (int i = 0; i < 4; i++) {
        float vv = acc[rt][ct][i] + (EPI == 4 ? bias[row + i] : bcol);
        size_t idx = (size_t)(row + i) * Ndim + col;
        if (EPI == 0 || EPI == 4) {
          ((__bf16*)Cout)[idx] = (__bf16)vv;
        } else if (EPI == 2) {
          ((float*)Cout)[idx] = vv + resid[idx];
        } else {
          ((__bf16*)Cout)[idx] = (__bf16)(0.5f * vv * (1.f + erff(vv * 0.70710678118f)));
        }
      }
    }
  }
}

// ---------------- flash attention + fused geo-bias, KV-split waves ---------
// No online max (logits bounded ~62): o,l are plain sums, so the KV axis
// splits across wave pairs and partials just add. Block: 64 Q-rows;
// wave w: nhalf=w&1 (row group), khalf=w>>1 (KV half, 16 iters each).
__global__ __launch_bounds__(256, 4) void k_flash(
    const __bf16* __restrict__ Q, const __bf16* __restrict__ K,
    const __bf16* __restrict__ Vt, const __bf16* __restrict__ Gq,
    const __bf16* __restrict__ Gk, const float* __restrict__ als,
    const float* __restrict__ psc, const float* __restrict__ nsc,
    __bf16* __restrict__ Out) {
  const int h = blockIdx.y, b = blockIdx.z;
  const int w = threadIdx.x >> 6, lane = threadIdx.x & 63;
  const int quad = lane >> 4, l15 = lane & 15;
  const int nhalf = w & 1, khalf = w >> 1;
  const int row0 = blockIdx.x * 64 + nhalf * 32;
  const float sc = __expf(als[0]) * 0.125f;
  const float pos = psc[0], neg = nsc[0];
  __shared__ __align__(16) __bf16 plds[4][32][72];  // 18432 B; aliased below

  const __bf16* Qb = Q + ((size_t)(b * NN + row0)) * DB + h * DHD;
  const __bf16* Kb = K + ((size_t)b * NM) * DB + h * DHD;
  const __bf16* Vb = Vt + (size_t)(h * DHD) * (NB * NM) + (size_t)b * NM;
  const __bf16* Gqb = Gq + (size_t)(b * NN + row0) * DP;
  const __bf16* Gkb = Gk + (size_t)b * NM * DP;

  bf16x8 qf[2][2], gqf[2][2];
#pragma unroll
  for (int rt = 0; rt < 2; rt++)
#pragma unroll
    for (int ks = 0; ks < 2; ks++) {
      qf[rt][ks] = *(const bf16x8*)(Qb + (size_t)(rt * 16 + l15) * DB + ks * 32 + quad * 8);
      gqf[rt][ks] = *(const bf16x8*)(Gqb + (size_t)(rt * 16 + l15) * DP + ks * 32 + quad * 8);
    }

  float lrow[2][4] = {};
  f32x4 oacc[2][4] = {};
  f32x4 z4 = {0.f, 0.f, 0.f, 0.f};

  const int mlo = khalf * 1024, mhi = mlo + 1024;
  for (int m0 = mlo; m0 < mhi; m0 += 64) {
    bf16x8 kf[4][2], gkf[4][2];
#pragma unroll
    for (int ct = 0; ct < 4; ct++)
#pragma unroll
      for (int ks = 0; ks < 2; ks++) {
        kf[ct][ks] = *(const bf16x8*)(Kb + (size_t)(m0 + ct * 16 + l15) * DB + ks * 32 + quad * 8);
        gkf[ct][ks] = *(const bf16x8*)(Gkb + (size_t)(m0 + ct * 16 + l15) * DP + ks * 32 + quad * 8);
      }
#pragma unroll
    for (int rt = 0; rt < 2; rt++)
#pragma unroll
      for (int ct = 0; ct < 4; ct++) {
        f32x4 s = mfma16(qf[rt][1], kf[ct][1], mfma16(qf[rt][0], kf[ct][0], z4));
        f32x4 bg = mfma16(gqf[rt][1], gkf[ct][1], mfma16(gqf[rt][0], gkf[ct][0], z4));
#pragma unroll
        for (int i = 0; i < 4; i++) {
          float bb = bg[i];
          float fb = bb > 0.f ? bb * pos : bb * neg;
          float p = __expf(s[i] * sc + fb);
          lrow[rt][i] += p;
          plds[w][rt * 16 + quad * 4 + i][ct * 16 + l15] = (__bf16)p;
        }
      }
    // P (C-layout) -> LDS -> A-frags; per-wave slice, lgkmcnt orders it
    bf16x8 pf[2][2], vf[4][2];
#pragma unroll
    for (int rt = 0; rt < 2; rt++)
#pragma unroll
      for (int ms = 0; ms < 2; ms++)
        pf[rt][ms] = *(const bf16x8*)&plds[w][rt * 16 + l15][ms * 32 + quad * 8];
#pragma unroll
    for (int dt = 0; dt < 4; dt++)
#pragma unroll
      for (int ms = 0; ms < 2; ms++)
        vf[dt][ms] = *(const bf16x8*)(Vb + (size_t)(dt * 16 + l15) * (NB * NM) + m0 + ms * 32 + quad * 8);
#pragma unroll
    for (int rt = 0; rt < 2; rt++)
#pragma unroll
      for (int dt = 0; dt < 4; dt++) {
        oacc[rt][dt] = mfma16(pf[rt][0], vf[dt][0], oacc[rt][dt]);
        oacc[rt][dt] = mfma16(pf[rt][1], vf[dt][1], oacc[rt][dt]);
      }
  }
  // reduce l over the 16 column-lanes (per wave, its own KV half)
  float lred[2][4];
#pragma unroll
  for (int rt = 0; rt < 2; rt++)
#pragma unroll
    for (int i = 0; i < 4; i++) {
      float l = lrow[rt][i];
#pragma unroll
      for (int o = 1; o < 16; o <<= 1) l += __shfl_xor(l, o, 64);
      lred[rt][i] = l;
    }
  // combine KV halves through LDS (aliases plds; all P use is done)
  __syncthreads();
  float* cf = (float*)plds;
  const int cb = nhalf * 32 * 68;
  if (khalf) {
#pragma unroll
    for (int rt = 0; rt < 2; rt++)
#pragma unroll
      for (int i = 0; i < 4; i++) {
        int r = rt * 16 + quad * 4 + i;
#pragma unroll
        for (int dt = 0; dt < 4; dt++)
          cf[cb + r * 68 + dt * 16 + l15] = oacc[rt][dt][i];
        if (l15 == 0) cf[cb + r * 68 + 64] = lred[rt][i];
      }
  }
  __syncthreads();
  if (!khalf) {
#pragma unroll
    for (int rt = 0; rt < 2; rt++)
#pragma unroll
      for (int i = 0; i < 4; i++) {
        int r = rt * 16 + quad * 4 + i;
        float inv = 1.f / (lred[rt][i] + cf[cb + r * 68 + 64]);
#pragma unroll
        for (int dt = 0; dt < 4; dt++) {
          float o = oacc[rt][dt][i] + cf[cb + r * 68 + dt * 16 + l15];
          Out[(size_t)(b * NN + row0 + r) * DB + h * DHD + dt * 16 + l15] =
              (__bf16)(o * inv);
        }
      }
  }
}

// ---------------------------------------------------------------------------
extern "C" void kernel_launch(void* const* d_in, const int* in_sizes, int n_in,
                              void* d_out, int out_size, void* d_ws, size_t ws_size,
                              hipStream_t stream) {
  const float* dataset = (const float*)d_in[0];
  const float* visual = (const float*)d_in[1];
  const float* wq_w = (const float*)d_in[2];
  const float* wq_b = (const float*)d_in[3];
  const float* wk_w = (const float*)d_in[4];
  const float* wk_b = (const float*)d_in[5];
  const float* wv_w = (const float*)d_in[6];
  const float* wv_b = (const float*)d_in[7];
  const float* wo_w = (const float*)d_in[8];
  const float* wo_b = (const float*)d_in[9];
  const float* gq_w = (const float*)d_in[10];
  const float* gq_b = (const float*)d_in[11];
  const float* gk_w = (const float*)d_in[12];
  const float* gk_b = (const float*)d_in[13];
  const float* pos_scale = (const float*)d_in[14];
  const float* neg_scale = (const float*)d_in[15];
  const float* als = (const float*)d_in[16];
  const float* ln_q_g = (const float*)d_in[17];
  const float* ln_q_b = (const float*)d_in[18];
  const float* ln_kv_g = (const float*)d_in[19];
  const float* ln_kv_b = (const float*)d_in[20];
  const float* ln_out_g = (const float*)d_in[21];
  const float* ln_out_b = (const float*)d_in[22];
  const float* ff1_w = (const float*)d_in[23];
  const float* ff1_b = (const float*)d_in[24];
  const float* ff2_w = (const float*)d_in[25];
  const float* ff2_b = (const float*)d_in[26];

  char* ws = (char*)d_ws;
  size_t off = 0;
  auto alloc = [&](size_t bytes) {
    size_t o = off;
    off += (bytes + 255) & ~(size_t)255;
    return o;
  };
  __bf16* t_wq = (__bf16*)(ws + alloc((size_t)1024 * 1024 * 2));
  __bf16* t_wk = (__bf16*)(ws + alloc((size_t)1024 * 1024 * 2));
  __bf16* t_wv = (__bf16*)(ws + alloc((size_t)1024 * 1024 * 2));
  __bf16* t_wo = (__bf16*)(ws + alloc((size_t)1024 * 1024 * 2));
  __bf16* t_ff1 = (__bf16*)(ws + alloc((size_t)2048 * 1024 * 2));
  __bf16* t_ff2 = (__bf16*)(ws + alloc((size_t)1024 * 2048 * 2));
  __bf16* t_gq = (__bf16*)(ws + alloc((size_t)64 * 1024 * 2));
  __bf16* t_gk = (__bf16*)(ws + alloc((size_t)64 * 1024 * 2));
  size_t qin_off = alloc((size_t)4096 * 1024 * 2);   // aliased as hbuf later
  size_t kvin_off = alloc((size_t)8192 * 1024 * 2);  // aliased as out1(f32) later
  __bf16* qin = (__bf16*)(ws + qin_off);
  __bf16* kvin = (__bf16*)(ws + kvin_off);
  __bf16* geoq = (__bf16*)(ws + alloc((size_t)4096 * 64 * 2));
  __bf16* geok = (__bf16*)(ws + alloc((size_t)8192 * 64 * 2));
  float* sums = (float*)(ws + alloc((size_t)2 * 4 * 64 * 4));
  __bf16* qb = (__bf16*)(ws + alloc((size_t)4096 * 1024 * 2));
  __bf16* kb = (__bf16*)(ws + alloc((size_t)8192 * 1024 * 2));
  __bf16* vtb = (__bf16*)(ws + alloc((size_t)1024 * 8192 * 2));  // V^T [ch][tok]
  __bf16* attn = (__bf16*)(ws + alloc((size_t)4096 * 1024 * 2));
  __bf16* ffh = (__bf16*)(ws + alloc((size_t)4096 * 2048 * 2));
  // aliases (lifetimes disjoint):
  float* out1 = (float*)(ws + kvin_off);   // f32 [4096,1024] over kv_in
  __bf16* hbuf = (__bf16*)(ws + qin_off);  // bf16 [4096,1024] over q_in
  float* outp = (float*)d_out;

  dim3 blk(256);
  // 1. all weight transposes in one launch
  k_transpose_all<<<8320, blk, 0, stream>>>(wq_w, wk_w, wv_w, wo_w, ff1_w, ff2_w,
                                            gq_w, gk_w, t_wq, t_wk, t_wv, t_wo,
                                            t_ff1, t_ff2, t_gq, t_gk);
  // 2. both input layernorms in one launch
  k_layernorm2<<<12288, blk, 0, stream>>>(dataset, ln_q_g, ln_q_b, qin,
                                          visual, ln_kv_g, ln_kv_b, kvin);
  // 3. geo path
  k_geo<<<384, blk, 0, stream>>>(qin, kvin, t_gq, t_gk, gq_b, gk_b, geoq, geok);
  hipMemsetAsync(sums, 0, 2 * 4 * 64 * 4, stream);
  k_l2sum<<<dim3(16, 4, 2), blk, 0, stream>>>(geoq, geok, sums);
  k_l2scale<<<dim3(16, 4), blk, 0, stream>>>(geok, sums);
  // 4. Q/K projections; V^T directly via operand swap (row bias)
  k_gemm128<0><<<dim3(8, 32), blk, 0, stream>>>(qin, t_wq, wq_b, nullptr, qb,
                                                4096, 1024, 1024);
  k_gemm128<0><<<dim3(8, 64), blk, 0, stream>>>(kvin, t_wk, wk_b, nullptr, kb,
                                                8192, 1024, 1024);
  k_gemm128<4><<<dim3(64, 8), blk, 0, stream>>>(t_wv, kvin, wv_b, nullptr, vtb,
                                                1024, 8192, 1024);
  // 5. flash attention (bias fused, KV-split waves)
  k_flash<<<dim3(16, 16, 4), blk, 0, stream>>>(qb, kb, vtb, geoq, geok, als,
                                               pos_scale, neg_scale, attn);
  // 6. output projection + residual, LN, FFN
  k_gemm128<2><<<dim3(8, 32), blk, 0, stream>>>(attn, t_wo, wo_b, dataset, out1,
                                                4096, 1024, 1024);
  k_layernorm<<<4096, blk, 0, stream>>>(out1, ln_out_g, ln_out_b, hbuf);
  k_gemm128<3><<<dim3(16, 32), blk, 0, stream>>>(hbuf, t_ff1, ff1_b, nullptr, ffh,
                                                 4096, 2048, 1024);
  k_gemm128<2><<<dim3(8, 32), blk, 0, stream>>>(ffh, t_ff2, ff2_b, out1, outp,
                                                4096, 1024, 2048);
}

// Round 4
// 563.496 us; speedup vs baseline: 1.3476x; 1.3476x over previous
//
#include <hip/hip_runtime.h>

// ---------------------------------------------------------------------------
// BiasCrossAttentionFusion on gfx950 — round 3.
//   R3 vs R2 (759us): single fix. R2's flash __launch_bounds__(256,4) forced
//   VGPR=64 -> full K-loop working set spilled to scratch (WRITE_SIZE 8MB ->
//   627MB, FETCH 140->740MB). Revert to (256,2): allocator free (~90 VGPR),
//   actual occupancy still ~4-5 blocks/CU from the 1024-block KV-split grid.
//   Everything else identical to R2.
// ---------------------------------------------------------------------------

typedef __bf16 bf16x8 __attribute__((ext_vector_type(8)));
typedef float  f32x4  __attribute__((ext_vector_type(4)));

__device__ inline f32x4 mfma16(bf16x8 a, bf16x8 b, f32x4 c) {
  return __builtin_amdgcn_mfma_f32_16x16x32_bf16(a, b, c, 0, 0, 0);
}

__device__ inline void glds16(const void* g, void* l) {
  __builtin_amdgcn_global_load_lds(
      (const __attribute__((address_space(1))) void*)g,
      (__attribute__((address_space(3))) void*)l, 16, 0, 0);
}

#define DB 1024
#define DH 16
#define DHD 64
#define DP 64
#define NB 4
#define NN 1024
#define NM 2048

// ---------------- all weight transposes (f32 [K,O] -> bf16 [O,K]) ----------
__global__ __launch_bounds__(256) void k_transpose_all(
    const float* __restrict__ w0, const float* __restrict__ w1,
    const float* __restrict__ w2, const float* __restrict__ w3,
    const float* __restrict__ f1, const float* __restrict__ f2,
    const float* __restrict__ g0, const float* __restrict__ g1,
    __bf16* __restrict__ o0, __bf16* __restrict__ o1,
    __bf16* __restrict__ o2, __bf16* __restrict__ o3,
    __bf16* __restrict__ of1, __bf16* __restrict__ of2,
    __bf16* __restrict__ og0, __bf16* __restrict__ og1) {
  __shared__ float tile[32][33];
  int id = blockIdx.x;
  const float* in;
  __bf16* out;
  int K, O, x, y;
  if (id < 4096) {
    int mi = id >> 10, r = id & 1023;
    in = mi == 0 ? w0 : mi == 1 ? w1 : mi == 2 ? w2 : w3;
    out = mi == 0 ? o0 : mi == 1 ? o1 : mi == 2 ? o2 : o3;
    K = 1024; O = 1024; x = r & 31; y = r >> 5;
  } else if (id < 6144) {
    int r = id - 4096; in = f1; out = of1; K = 1024; O = 2048; x = r & 63; y = r >> 6;
  } else if (id < 8192) {
    int r = id - 6144; in = f2; out = of2; K = 2048; O = 1024; x = r & 31; y = r >> 5;
  } else if (id < 8256) {
    int r = id - 8192; in = g0; out = og0; K = 1024; O = 64; x = r & 1; y = r >> 1;
  } else {
    int r = id - 8256; in = g1; out = og1; K = 1024; O = 64; x = r & 1; y = r >> 1;
  }
  int k0 = y * 32, o0c = x * 32;
  int tx = threadIdx.x & 31, ty = threadIdx.x >> 5;
#pragma unroll
  for (int r = ty; r < 32; r += 8)
    tile[r][tx] = in[(size_t)(k0 + r) * O + (o0c + tx)];
  __syncthreads();
#pragma unroll
  for (int r = ty; r < 32; r += 8)
    out[(size_t)(o0c + r) * K + (k0 + tx)] = (__bf16)tile[tx][r];
}

// ---------------- LayerNorm D=1024, one block/row, bf16 out ----------------
__device__ inline void ln_body(const float* __restrict__ x,
                               const float* __restrict__ g,
                               const float* __restrict__ bb,
                               __bf16* __restrict__ y, size_t row) {
  int t = threadIdx.x;
  float4 v = ((const float4*)(x + row * 1024))[t];
  float s = v.x + v.y + v.z + v.w;
  float ss = v.x * v.x + v.y * v.y + v.z * v.z + v.w * v.w;
#pragma unroll
  for (int o = 32; o; o >>= 1) {
    s += __shfl_down(s, o, 64);
    ss += __shfl_down(ss, o, 64);
  }
  __shared__ float r1[4], r2[4];
  if ((t & 63) == 0) { r1[t >> 6] = s; r2[t >> 6] = ss; }
  __syncthreads();
  s = r1[0] + r1[1] + r1[2] + r1[3];
  ss = r2[0] + r2[1] + r2[2] + r2[3];
  float mu = s * (1.f / 1024.f);
  float rstd = rsqrtf(ss * (1.f / 1024.f) - mu * mu + 1e-5f);
  float4 gv = ((const float4*)g)[t];
  float4 bv = ((const float4*)bb)[t];
  __bf16* yr = y + row * 1024 + t * 4;
  yr[0] = (__bf16)((v.x - mu) * rstd * gv.x + bv.x);
  yr[1] = (__bf16)((v.y - mu) * rstd * gv.y + bv.y);
  yr[2] = (__bf16)((v.z - mu) * rstd * gv.z + bv.z);
  yr[3] = (__bf16)((v.w - mu) * rstd * gv.w + bv.w);
}

__global__ __launch_bounds__(256) void k_layernorm(
    const float* __restrict__ x, const float* __restrict__ g,
    const float* __restrict__ bb, __bf16* __restrict__ y) {
  ln_body(x, g, bb, y, blockIdx.x);
}

__global__ __launch_bounds__(256) void k_layernorm2(
    const float* __restrict__ x1, const float* __restrict__ g1,
    const float* __restrict__ b1, __bf16* __restrict__ y1,
    const float* __restrict__ x2, const float* __restrict__ g2,
    const float* __restrict__ b2, __bf16* __restrict__ y2) {
  int row = blockIdx.x;
  if (row < 4096) ln_body(x1, g1, b1, y1, row);
  else ln_body(x2, g2, b2, y2, row - 4096);
}

// ---------------- geo projections: q(128 blk) + kv(256 blk), 32x64 tiles ---
__global__ __launch_bounds__(256) void k_geo(
    const __bf16* __restrict__ qin, const __bf16* __restrict__ kvin,
    const __bf16* __restrict__ gqw, const __bf16* __restrict__ gkw,
    const float* __restrict__ gqb, const float* __restrict__ gkb,
    __bf16* __restrict__ geoq, __bf16* __restrict__ geok) {
  const int blk = blockIdx.x;
  const bool isq = blk < 128;
  const __bf16* A = isq ? qin : kvin;
  const __bf16* Bt = isq ? gqw : gkw;
  const float* bias = isq ? gqb : gkb;
  __bf16* C = isq ? geoq : geok;
  const int row0 = (isq ? blk : blk - 128) * 32;
  __shared__ __align__(16) __bf16 As[32][72], Bs[64][72];
  const int t = threadIdx.x, lane = t & 63, w = t >> 6;
  const int quad = lane >> 4, l15 = lane & 15;
  const int wr = w >> 1, wc = w & 1;
  const int sr = t >> 3, skc = (t & 7) * 8;
  const __bf16* aP = A + (size_t)(row0 + sr) * 1024 + skc;
  const __bf16* bP0 = Bt + (size_t)sr * 1024 + skc;
  const __bf16* bP1 = Bt + (size_t)(sr + 32) * 1024 + skc;
  bf16x8 av = *(const bf16x8*)aP;
  bf16x8 bv0 = *(const bf16x8*)bP0;
  bf16x8 bv1 = *(const bf16x8*)bP1;
  f32x4 acc[2] = {};
  for (int k0 = 0; k0 < 1024; k0 += 64) {
    __syncthreads();
    *(bf16x8*)&As[sr][skc] = av;
    *(bf16x8*)&Bs[sr][skc] = bv0;
    *(bf16x8*)&Bs[sr + 32][skc] = bv1;
    __syncthreads();
    if (k0 + 64 < 1024) {
      av = *(const bf16x8*)(aP + k0 + 64);
      bv0 = *(const bf16x8*)(bP0 + k0 + 64);
      bv1 = *(const bf16x8*)(bP1 + k0 + 64);
    }
#pragma unroll
    for (int ks = 0; ks < 2; ks++) {
      bf16x8 af = *(const bf16x8*)&As[wr * 16 + l15][ks * 32 + quad * 8];
#pragma unroll
      for (int ct = 0; ct < 2; ct++) {
        bf16x8 bfr = *(const bf16x8*)&Bs[wc * 32 + ct * 16 + l15][ks * 32 + quad * 8];
        acc[ct] = mfma16(af, bfr, acc[ct]);
      }
    }
  }
#pragma unroll
  for (int ct = 0; ct < 2; ct++) {
    int col = wc * 32 + ct * 16 + l15;
    float bc = bias[col];
#pragma unroll
    for (int i = 0; i < 4; i++) {
      int row = row0 + wr * 16 + quad * 4 + i;
      C[(size_t)row * 64 + col] = (__bf16)(acc[ct][i] + bc);
    }
  }
}

// ---------------- l2 norms, phase 1: column sum-of-squares -----------------
// sums layout: [z(0=q,1=k)][b][64] f32
__global__ __launch_bounds__(256) void k_l2sum(
    const __bf16* __restrict__ gq, const __bf16* __restrict__ gk,
    float* __restrict__ sums) {
  int chunk = blockIdx.x, b = blockIdx.y, z = blockIdx.z;
  if (z == 0 && chunk >= 8) return;
  const __bf16* src = z ? gk : gq;
  int rows = z ? 2048 : 1024;
  const unsigned* base = (const unsigned*)(src + (size_t)b * rows * 64) + chunk * 128 * 32;
  int t = threadIdx.x, c = t & 31, ro = t >> 5;
  float s0 = 0.f, s1 = 0.f;
  for (int r = ro; r < 128; r += 8) {
    unsigned u = base[r * 32 + c];
    float f0 = __uint_as_float(u << 16);
    float f1 = __uint_as_float(u & 0xffff0000u);
    s0 += f0 * f0;
    s1 += f1 * f1;
  }
  __shared__ float ls[64];
  if (t < 64) ls[t] = 0.f;
  __syncthreads();
  atomicAdd(&ls[c * 2], s0);
  atomicAdd(&ls[c * 2 + 1], s1);
  __syncthreads();
  if (t < 64) atomicAdd(&sums[z * 256 + b * 64 + t], ls[t]);
}

// ---------------- l2 phase 2: scale geo_k by 1/(||q_p||*||k_p||) -----------
__global__ __launch_bounds__(256) void k_l2scale(
    __bf16* __restrict__ gk, const float* __restrict__ sums) {
  int chunk = blockIdx.x, b = blockIdx.y;
  unsigned* base = (unsigned*)(gk + (size_t)b * 2048 * 64) + chunk * 128 * 32;
  int t = threadIdx.x, c = t & 31, ro = t >> 5;
  float sq0 = sums[b * 64 + c * 2], sq1 = sums[b * 64 + c * 2 + 1];
  float sk0 = sums[256 + b * 64 + c * 2], sk1 = sums[256 + b * 64 + c * 2 + 1];
  float m0 = 1.f / (fmaxf(sqrtf(sq0), 1e-12f) * fmaxf(sqrtf(sk0), 1e-12f));
  float m1 = 1.f / (fmaxf(sqrtf(sq1), 1e-12f) * fmaxf(sqrtf(sk1), 1e-12f));
  for (int r = ro; r < 128; r += 8) {
    unsigned u = base[r * 32 + c];
    float f0 = __uint_as_float(u << 16) * m0;
    float f1 = __uint_as_float(u & 0xffff0000u) * m1;
    unsigned short h0 = __builtin_bit_cast(unsigned short, (__bf16)f0);
    unsigned short h1 = __builtin_bit_cast(unsigned short, (__bf16)f1);
    base[r * 32 + c] = (unsigned)h0 | ((unsigned)h1 << 16);
  }
}

// ---------------- big GEMM: m97 structure, 128x128 tile, global_load_lds ---
// EPI: 0 = +bias(col) -> bf16 | 2 = +bias(col) +residual -> f32
//      3 = +bias(col), exact gelu -> bf16 | 4 = +bias(row) -> bf16 (V^T)
template <int EPI>
__global__ __launch_bounds__(256, 2) void k_gemm128(
    const __bf16* __restrict__ A, const __bf16* __restrict__ Bt,
    const float* __restrict__ bias, const float* __restrict__ resid,
    void* __restrict__ Cout, int Mdim, int Ndim, int Kdim) {
  __shared__ __align__(16) __bf16 As[128 * 32];
  __shared__ __align__(16) __bf16 Bs[128 * 32];
  const int m0 = blockIdx.y * 128, n0 = blockIdx.x * 128;
  const int t = threadIdx.x, lane = t & 63, w = t >> 6;
  const int quad = lane >> 4, l15 = lane & 15;
  const int wr = w >> 1, wc = w & 1;
  const int srow = lane >> 2, scol = (lane & 3) * 8;
  const __bf16* aS0 = A + (size_t)(m0 + w * 32 + srow) * Kdim + scol;
  const __bf16* bS0 = Bt + (size_t)(n0 + w * 32 + srow) * Kdim + scol;
  const size_t K16 = (size_t)16 * Kdim;
  __bf16* lA0 = &As[(w * 32) * 32];
  __bf16* lB0 = &Bs[(w * 32) * 32];

  f32x4 acc[4][4] = {};
  for (int k0 = 0; k0 < Kdim; k0 += 32) {
    __syncthreads();
    glds16(aS0 + k0, lA0);
    glds16(aS0 + K16 + k0, lA0 + 16 * 32);
    glds16(bS0 + k0, lB0);
    glds16(bS0 + K16 + k0, lB0 + 16 * 32);
    __syncthreads();
    bf16x8 af[4], bg[4];
#pragma unroll
    for (int rt = 0; rt < 4; rt++)
      af[rt] = *(const bf16x8*)&As[(wr * 64 + rt * 16 + l15) * 32 + quad * 8];
#pragma unroll
    for (int ct = 0; ct < 4; ct++)
      bg[ct] = *(const bf16x8*)&Bs[(wc * 64 + ct * 16 + l15) * 32 + quad * 8];
#pragma unroll
    for (int rt = 0; rt < 4; rt++)
#pragma unroll
      for (int ct = 0; ct < 4; ct++)
        acc[rt][ct] = mfma16(af[rt], bg[ct], acc[rt][ct]);
  }
#pragma unroll
  for (int rt = 0; rt < 4; rt++) {
    int row = m0 + wr * 64 + rt * 16 + quad * 4;
#pragma unroll
    for (int ct = 0; ct < 4; ct++) {
      int col = n0 + wc * 64 + ct * 16 + l15;
      float bcol = (EPI == 4) ? 0.f : bias[col];
#pragma unroll
      for (int i = 0; i < 4; i++) {
        float vv = acc[rt][ct][i] + (EPI == 4 ? bias[row + i] : bcol);
        size_t idx = (size_t)(row + i) * Ndim + col;
        if (EPI == 0 || EPI == 4) {
          ((__bf16*)Cout)[idx] = (__bf16)vv;
        } else if (EPI == 2) {
          ((float*)Cout)[idx] = vv + resid[idx];
        } else {
          ((__bf16*)Cout)[idx] = (__bf16)(0.5f * vv * (1.f + erff(vv * 0.70710678118f)));
        }
      }
    }
  }
}

// ---------------- flash attention + fused geo-bias, KV-split waves ---------
// No online max (logits bounded ~62): o,l are plain sums, so the KV axis
// splits across wave pairs and partials just add. Block: 64 Q-rows;
// wave w: nhalf=w&1 (row group), khalf=w>>1 (KV half, 16 iters each).
// NOTE: launch_bounds min-waves MUST stay at 2 — forcing 4 clamps VGPR to 64
// and spills the whole K-loop working set (R2: WRITE_SIZE 8MB -> 627MB).
__global__ __launch_bounds__(256, 2) void k_flash(
    const __bf16* __restrict__ Q, const __bf16* __restrict__ K,
    const __bf16* __restrict__ Vt, const __bf16* __restrict__ Gq,
    const __bf16* __restrict__ Gk, const float* __restrict__ als,
    const float* __restrict__ psc, const float* __restrict__ nsc,
    __bf16* __restrict__ Out) {
  const int h = blockIdx.y, b = blockIdx.z;
  const int w = threadIdx.x >> 6, lane = threadIdx.x & 63;
  const int quad = lane >> 4, l15 = lane & 15;
  const int nhalf = w & 1, khalf = w >> 1;
  const int row0 = blockIdx.x * 64 + nhalf * 32;
  const float sc = __expf(als[0]) * 0.125f;
  const float pos = psc[0], neg = nsc[0];
  __shared__ __align__(16) __bf16 plds[4][32][72];  // 18432 B; aliased below

  const __bf16* Qb = Q + ((size_t)(b * NN + row0)) * DB + h * DHD;
  const __bf16* Kb = K + ((size_t)b * NM) * DB + h * DHD;
  const __bf16* Vb = Vt + (size_t)(h * DHD) * (NB * NM) + (size_t)b * NM;
  const __bf16* Gqb = Gq + (size_t)(b * NN + row0) * DP;
  const __bf16* Gkb = Gk + (size_t)b * NM * DP;

  bf16x8 qf[2][2], gqf[2][2];
#pragma unroll
  for (int rt = 0; rt < 2; rt++)
#pragma unroll
    for (int ks = 0; ks < 2; ks++) {
      qf[rt][ks] = *(const bf16x8*)(Qb + (size_t)(rt * 16 + l15) * DB + ks * 32 + quad * 8);
      gqf[rt][ks] = *(const bf16x8*)(Gqb + (size_t)(rt * 16 + l15) * DP + ks * 32 + quad * 8);
    }

  float lrow[2][4] = {};
  f32x4 oacc[2][4] = {};
  f32x4 z4 = {0.f, 0.f, 0.f, 0.f};

  const int mlo = khalf * 1024, mhi = mlo + 1024;
  for (int m0 = mlo; m0 < mhi; m0 += 64) {
    bf16x8 kf[4][2], gkf[4][2];
#pragma unroll
    for (int ct = 0; ct < 4; ct++)
#pragma unroll
      for (int ks = 0; ks < 2; ks++) {
        kf[ct][ks] = *(const bf16x8*)(Kb + (size_t)(m0 + ct * 16 + l15) * DB + ks * 32 + quad * 8);
        gkf[ct][ks] = *(const bf16x8*)(Gkb + (size_t)(m0 + ct * 16 + l15) * DP + ks * 32 + quad * 8);
      }
#pragma unroll
    for (int rt = 0; rt < 2; rt++)
#pragma unroll
      for (int ct = 0; ct < 4; ct++) {
        f32x4 s = mfma16(qf[rt][1], kf[ct][1], mfma16(qf[rt][0], kf[ct][0], z4));
        f32x4 bg = mfma16(gqf[rt][1], gkf[ct][1], mfma16(gqf[rt][0], gkf[ct][0], z4));
#pragma unroll
        for (int i = 0; i < 4; i++) {
          float bb = bg[i];
          float fb = bb > 0.f ? bb * pos : bb * neg;
          float p = __expf(s[i] * sc + fb);
          lrow[rt][i] += p;
          plds[w][rt * 16 + quad * 4 + i][ct * 16 + l15] = (__bf16)p;
        }
      }
    // P (C-layout) -> LDS -> A-frags; per-wave slice, lgkmcnt orders it
    bf16x8 pf[2][2], vf[4][2];
#pragma unroll
    for (int rt = 0; rt < 2; rt++)
#pragma unroll
      for (int ms = 0; ms < 2; ms++)
        pf[rt][ms] = *(const bf16x8*)&plds[w][rt * 16 + l15][ms * 32 + quad * 8];
#pragma unroll
    for (int dt = 0; dt < 4; dt++)
#pragma unroll
      for (int ms = 0; ms < 2; ms++)
        vf[dt][ms] = *(const bf16x8*)(Vb + (size_t)(dt * 16 + l15) * (NB * NM) + m0 + ms * 32 + quad * 8);
#pragma unroll
    for (int rt = 0; rt < 2; rt++)
#pragma unroll
      for (int dt = 0; dt < 4; dt++) {
        oacc[rt][dt] = mfma16(pf[rt][0], vf[dt][0], oacc[rt][dt]);
        oacc[rt][dt] = mfma16(pf[rt][1], vf[dt][1], oacc[rt][dt]);
      }
  }
  // reduce l over the 16 column-lanes (per wave, its own KV half)
  float lred[2][4];
#pragma unroll
  for (int rt = 0; rt < 2; rt++)
#pragma unroll
    for (int i = 0; i < 4; i++) {
      float l = lrow[rt][i];
#pragma unroll
      for (int o = 1; o < 16; o <<= 1) l += __shfl_xor(l, o, 64);
      lred[rt][i] = l;
    }
  // combine KV halves through LDS (aliases plds; all P use is done)
  __syncthreads();
  float* cf = (float*)plds;
  const int cb = nhalf * 32 * 68;
  if (khalf) {
#pragma unroll
    for (int rt = 0; rt < 2; rt++)
#pragma unroll
      for (int i = 0; i < 4; i++) {
        int r = rt * 16 + quad * 4 + i;
#pragma unroll
        for (int dt = 0; dt < 4; dt++)
          cf[cb + r * 68 + dt * 16 + l15] = oacc[rt][dt][i];
        if (l15 == 0) cf[cb + r * 68 + 64] = lred[rt][i];
      }
  }
  __syncthreads();
  if (!khalf) {
#pragma unroll
    for (int rt = 0; rt < 2; rt++)
#pragma unroll
      for (int i = 0; i < 4; i++) {
        int r = rt * 16 + quad * 4 + i;
        float inv = 1.f / (lred[rt][i] + cf[cb + r * 68 + 64]);
#pragma unroll
        for (int dt = 0; dt < 4; dt++) {
          float o = oacc[rt][dt][i] + cf[cb + r * 68 + dt * 16 + l15];
          Out[(size_t)(b * NN + row0 + r) * DB + h * DHD + dt * 16 + l15] =
              (__bf16)(o * inv);
        }
      }
  }
}

// ---------------------------------------------------------------------------
extern "C" void kernel_launch(void* const* d_in, const int* in_sizes, int n_in,
                              void* d_out, int out_size, void* d_ws, size_t ws_size,
                              hipStream_t stream) {
  const float* dataset = (const float*)d_in[0];
  const float* visual = (const float*)d_in[1];
  const float* wq_w = (const float*)d_in[2];
  const float* wq_b = (const float*)d_in[3];
  const float* wk_w = (const float*)d_in[4];
  const float* wk_b = (const float*)d_in[5];
  const float* wv_w = (const float*)d_in[6];
  const float* wv_b = (const float*)d_in[7];
  const float* wo_w = (const float*)d_in[8];
  const float* wo_b = (const float*)d_in[9];
  const float* gq_w = (const float*)d_in[10];
  const float* gq_b = (const float*)d_in[11];
  const float* gk_w = (const float*)d_in[12];
  const float* gk_b = (const float*)d_in[13];
  const float* pos_scale = (const float*)d_in[14];
  const float* neg_scale = (const float*)d_in[15];
  const float* als = (const float*)d_in[16];
  const float* ln_q_g = (const float*)d_in[17];
  const float* ln_q_b = (const float*)d_in[18];
  const float* ln_kv_g = (const float*)d_in[19];
  const float* ln_kv_b = (const float*)d_in[20];
  const float* ln_out_g = (const float*)d_in[21];
  const float* ln_out_b = (const float*)d_in[22];
  const float* ff1_w = (const float*)d_in[23];
  const float* ff1_b = (const float*)d_in[24];
  const float* ff2_w = (const float*)d_in[25];
  const float* ff2_b = (const float*)d_in[26];

  char* ws = (char*)d_ws;
  size_t off = 0;
  auto alloc = [&](size_t bytes) {
    size_t o = off;
    off += (bytes + 255) & ~(size_t)255;
    return o;
  };
  __bf16* t_wq = (__bf16*)(ws + alloc((size_t)1024 * 1024 * 2));
  __bf16* t_wk = (__bf16*)(ws + alloc((size_t)1024 * 1024 * 2));
  __bf16* t_wv = (__bf16*)(ws + alloc((size_t)1024 * 1024 * 2));
  __bf16* t_wo = (__bf16*)(ws + alloc((size_t)1024 * 1024 * 2));
  __bf16* t_ff1 = (__bf16*)(ws + alloc((size_t)2048 * 1024 * 2));
  __bf16* t_ff2 = (__bf16*)(ws + alloc((size_t)1024 * 2048 * 2));
  __bf16* t_gq = (__bf16*)(ws + alloc((size_t)64 * 1024 * 2));
  __bf16* t_gk = (__bf16*)(ws + alloc((size_t)64 * 1024 * 2));
  size_t qin_off = alloc((size_t)4096 * 1024 * 2);   // aliased as hbuf later
  size_t kvin_off = alloc((size_t)8192 * 1024 * 2);  // aliased as out1(f32) later
  __bf16* qin = (__bf16*)(ws + qin_off);
  __bf16* kvin = (__bf16*)(ws + kvin_off);
  __bf16* geoq = (__bf16*)(ws + alloc((size_t)4096 * 64 * 2));
  __bf16* geok = (__bf16*)(ws + alloc((size_t)8192 * 64 * 2));
  float* sums = (float*)(ws + alloc((size_t)2 * 4 * 64 * 4));
  __bf16* qb = (__bf16*)(ws + alloc((size_t)4096 * 1024 * 2));
  __bf16* kb = (__bf16*)(ws + alloc((size_t)8192 * 1024 * 2));
  __bf16* vtb = (__bf16*)(ws + alloc((size_t)1024 * 8192 * 2));  // V^T [ch][tok]
  __bf16* attn = (__bf16*)(ws + alloc((size_t)4096 * 1024 * 2));
  __bf16* ffh = (__bf16*)(ws + alloc((size_t)4096 * 2048 * 2));
  // aliases (lifetimes disjoint):
  float* out1 = (float*)(ws + kvin_off);   // f32 [4096,1024] over kv_in
  __bf16* hbuf = (__bf16*)(ws + qin_off);  // bf16 [4096,1024] over q_in
  float* outp = (float*)d_out;

  dim3 blk(256);
  // 1. all weight transposes in one launch
  k_transpose_all<<<8320, blk, 0, stream>>>(wq_w, wk_w, wv_w, wo_w, ff1_w, ff2_w,
                                            gq_w, gk_w, t_wq, t_wk, t_wv, t_wo,
                                            t_ff1, t_ff2, t_gq, t_gk);
  // 2. both input layernorms in one launch
  k_layernorm2<<<12288, blk, 0, stream>>>(dataset, ln_q_g, ln_q_b, qin,
                                          visual, ln_kv_g, ln_kv_b, kvin);
  // 3. geo path
  k_geo<<<384, blk, 0, stream>>>(qin, kvin, t_gq, t_gk, gq_b, gk_b, geoq, geok);
  hipMemsetAsync(sums, 0, 2 * 4 * 64 * 4, stream);
  k_l2sum<<<dim3(16, 4, 2), blk, 0, stream>>>(geoq, geok, sums);
  k_l2scale<<<dim3(16, 4), blk, 0, stream>>>(geok, sums);
  // 4. Q/K projections; V^T directly via operand swap (row bias)
  k_gemm128<0><<<dim3(8, 32), blk, 0, stream>>>(qin, t_wq, wq_b, nullptr, qb,
                                                4096, 1024, 1024);
  k_gemm128<0><<<dim3(8, 64), blk, 0, stream>>>(kvin, t_wk, wk_b, nullptr, kb,
                                                8192, 1024, 1024);
  k_gemm128<4><<<dim3(64, 8), blk, 0, stream>>>(t_wv, kvin, wv_b, nullptr, vtb,
                                                1024, 8192, 1024);
  // 5. flash attention (bias fused, KV-split waves)
  k_flash<<<dim3(16, 16, 4), blk, 0, stream>>>(qb, kb, vtb, geoq, geok, als,
                                               pos_scale, neg_scale, attn);
  // 6. output projection + residual, LN, FFN
  k_gemm128<2><<<dim3(8, 32), blk, 0, stream>>>(attn, t_wo, wo_b, dataset, out1,
                                                4096, 1024, 1024);
  k_layernorm<<<4096, blk, 0, stream>>>(out1, ln_out_g, ln_out_b, hbuf);
  k_gemm128<3><<<dim3(16, 32), blk, 0, stream>>>(hbuf, t_ff1, ff1_b, nullptr, ffh,
                                                 4096, 2048, 1024);
  k_gemm128<2><<<dim3(8, 32), blk, 0, stream>>>(ffh, t_ff2, ff2_b, out1, outp,
                                                4096, 1024, 2048);
}

// Round 5
// 455.986 us; speedup vs baseline: 1.6653x; 1.2358x over previous
//
#include <hip/hip_runtime.h>

// ---------------------------------------------------------------------------
// BiasCrossAttentionFusion on gfx950 — round 4.
//   R4 vs R3 (563us, flash 194us): flash was bound by redundant strided K/Gk/V
//   loads per-wave (1.5GB L2 traffic), not grid TLP (R3 proved that). Rebuild:
//   * k_flash: 128 Q-rows/block; K/Gk/V 64x64 tiles staged once per block into
//     padded LDS (register round-trip, next-iter prefetch in regs — k_geo's
//     proven pipeline); all 4 waves share tiles. (b,h)-major block order for
//     XCD L2 locality. 4x less cache traffic, coalesced, latency hidden.
//   * qb/kb/vtb fused into one 1280-block launch (they are independent;
//     qb alone was 256 blocks = 1 block/CU).
// ---------------------------------------------------------------------------

typedef __bf16 bf16x8 __attribute__((ext_vector_type(8)));
typedef float  f32x4  __attribute__((ext_vector_type(4)));

__device__ inline f32x4 mfma16(bf16x8 a, bf16x8 b, f32x4 c) {
  return __builtin_amdgcn_mfma_f32_16x16x32_bf16(a, b, c, 0, 0, 0);
}

__device__ inline void glds16(const void* g, void* l) {
  __builtin_amdgcn_global_load_lds(
      (const __attribute__((address_space(1))) void*)g,
      (__attribute__((address_space(3))) void*)l, 16, 0, 0);
}

#define DB 1024
#define DH 16
#define DHD 64
#define DP 64
#define NB 4
#define NN 1024
#define NM 2048

// ---------------- all weight transposes (f32 [K,O] -> bf16 [O,K]) ----------
__global__ __launch_bounds__(256) void k_transpose_all(
    const float* __restrict__ w0, const float* __restrict__ w1,
    const float* __restrict__ w2, const float* __restrict__ w3,
    const float* __restrict__ f1, const float* __restrict__ f2,
    const float* __restrict__ g0, const float* __restrict__ g1,
    __bf16* __restrict__ o0, __bf16* __restrict__ o1,
    __bf16* __restrict__ o2, __bf16* __restrict__ o3,
    __bf16* __restrict__ of1, __bf16* __restrict__ of2,
    __bf16* __restrict__ og0, __bf16* __restrict__ og1) {
  __shared__ float tile[32][33];
  int id = blockIdx.x;
  const float* in;
  __bf16* out;
  int K, O, x, y;
  if (id < 4096) {
    int mi = id >> 10, r = id & 1023;
    in = mi == 0 ? w0 : mi == 1 ? w1 : mi == 2 ? w2 : w3;
    out = mi == 0 ? o0 : mi == 1 ? o1 : mi == 2 ? o2 : o3;
    K = 1024; O = 1024; x = r & 31; y = r >> 5;
  } else if (id < 6144) {
    int r = id - 4096; in = f1; out = of1; K = 1024; O = 2048; x = r & 63; y = r >> 6;
  } else if (id < 8192) {
    int r = id - 6144; in = f2; out = of2; K = 2048; O = 1024; x = r & 31; y = r >> 5;
  } else if (id < 8256) {
    int r = id - 8192; in = g0; out = og0; K = 1024; O = 64; x = r & 1; y = r >> 1;
  } else {
    int r = id - 8256; in = g1; out = og1; K = 1024; O = 64; x = r & 1; y = r >> 1;
  }
  int k0 = y * 32, o0c = x * 32;
  int tx = threadIdx.x & 31, ty = threadIdx.x >> 5;
#pragma unroll
  for (int r = ty; r < 32; r += 8)
    tile[r][tx] = in[(size_t)(k0 + r) * O + (o0c + tx)];
  __syncthreads();
#pragma unroll
  for (int r = ty; r < 32; r += 8)
    out[(size_t)(o0c + r) * K + (k0 + tx)] = (__bf16)tile[tx][r];
}

// ---------------- LayerNorm D=1024, one block/row, bf16 out ----------------
__device__ inline void ln_body(const float* __restrict__ x,
                               const float* __restrict__ g,
                               const float* __restrict__ bb,
                               __bf16* __restrict__ y, size_t row) {
  int t = threadIdx.x;
  float4 v = ((const float4*)(x + row * 1024))[t];
  float s = v.x + v.y + v.z + v.w;
  float ss = v.x * v.x + v.y * v.y + v.z * v.z + v.w * v.w;
#pragma unroll
  for (int o = 32; o; o >>= 1) {
    s += __shfl_down(s, o, 64);
    ss += __shfl_down(ss, o, 64);
  }
  __shared__ float r1[4], r2[4];
  if ((t & 63) == 0) { r1[t >> 6] = s; r2[t >> 6] = ss; }
  __syncthreads();
  s = r1[0] + r1[1] + r1[2] + r1[3];
  ss = r2[0] + r2[1] + r2[2] + r2[3];
  float mu = s * (1.f / 1024.f);
  float rstd = rsqrtf(ss * (1.f / 1024.f) - mu * mu + 1e-5f);
  float4 gv = ((const float4*)g)[t];
  float4 bv = ((const float4*)bb)[t];
  __bf16* yr = y + row * 1024 + t * 4;
  yr[0] = (__bf16)((v.x - mu) * rstd * gv.x + bv.x);
  yr[1] = (__bf16)((v.y - mu) * rstd * gv.y + bv.y);
  yr[2] = (__bf16)((v.z - mu) * rstd * gv.z + bv.z);
  yr[3] = (__bf16)((v.w - mu) * rstd * gv.w + bv.w);
}

__global__ __launch_bounds__(256) void k_layernorm(
    const float* __restrict__ x, const float* __restrict__ g,
    const float* __restrict__ bb, __bf16* __restrict__ y) {
  ln_body(x, g, bb, y, blockIdx.x);
}

__global__ __launch_bounds__(256) void k_layernorm2(
    const float* __restrict__ x1, const float* __restrict__ g1,
    const float* __restrict__ b1, __bf16* __restrict__ y1,
    const float* __restrict__ x2, const float* __restrict__ g2,
    const float* __restrict__ b2, __bf16* __restrict__ y2) {
  int row = blockIdx.x;
  if (row < 4096) ln_body(x1, g1, b1, y1, row);
  else ln_body(x2, g2, b2, y2, row - 4096);
}

// ---------------- geo projections: q(128 blk) + kv(256 blk), 32x64 tiles ---
__global__ __launch_bounds__(256) void k_geo(
    const __bf16* __restrict__ qin, const __bf16* __restrict__ kvin,
    const __bf16* __restrict__ gqw, const __bf16* __restrict__ gkw,
    const float* __restrict__ gqb, const float* __restrict__ gkb,
    __bf16* __restrict__ geoq, __bf16* __restrict__ geok) {
  const int blk = blockIdx.x;
  const bool isq = blk < 128;
  const __bf16* A = isq ? qin : kvin;
  const __bf16* Bt = isq ? gqw : gkw;
  const float* bias = isq ? gqb : gkb;
  __bf16* C = isq ? geoq : geok;
  const int row0 = (isq ? blk : blk - 128) * 32;
  __shared__ __align__(16) __bf16 As[32][72], Bs[64][72];
  const int t = threadIdx.x, lane = t & 63, w = t >> 6;
  const int quad = lane >> 4, l15 = lane & 15;
  const int wr = w >> 1, wc = w & 1;
  const int sr = t >> 3, skc = (t & 7) * 8;
  const __bf16* aP = A + (size_t)(row0 + sr) * 1024 + skc;
  const __bf16* bP0 = Bt + (size_t)sr * 1024 + skc;
  const __bf16* bP1 = Bt + (size_t)(sr + 32) * 1024 + skc;
  bf16x8 av = *(const bf16x8*)aP;
  bf16x8 bv0 = *(const bf16x8*)bP0;
  bf16x8 bv1 = *(const bf16x8*)bP1;
  f32x4 acc[2] = {};
  for (int k0 = 0; k0 < 1024; k0 += 64) {
    __syncthreads();
    *(bf16x8*)&As[sr][skc] = av;
    *(bf16x8*)&Bs[sr][skc] = bv0;
    *(bf16x8*)&Bs[sr + 32][skc] = bv1;
    __syncthreads();
    if (k0 + 64 < 1024) {
      av = *(const bf16x8*)(aP + k0 + 64);
      bv0 = *(const bf16x8*)(bP0 + k0 + 64);
      bv1 = *(const bf16x8*)(bP1 + k0 + 64);
    }
#pragma unroll
    for (int ks = 0; ks < 2; ks++) {
      bf16x8 af = *(const bf16x8*)&As[wr * 16 + l15][ks * 32 + quad * 8];
#pragma unroll
      for (int ct = 0; ct < 2; ct++) {
        bf16x8 bfr = *(const bf16x8*)&Bs[wc * 32 + ct * 16 + l15][ks * 32 + quad * 8];
        acc[ct] = mfma16(af, bfr, acc[ct]);
      }
    }
  }
#pragma unroll
  for (int ct = 0; ct < 2; ct++) {
    int col = wc * 32 + ct * 16 + l15;
    float bc = bias[col];
#pragma unroll
    for (int i = 0; i < 4; i++) {
      int row = row0 + wr * 16 + quad * 4 + i;
      C[(size_t)row * 64 + col] = (__bf16)(acc[ct][i] + bc);
    }
  }
}

// ---------------- l2 norms, phase 1: column sum-of-squares -----------------
__global__ __launch_bounds__(256) void k_l2sum(
    const __bf16* __restrict__ gq, const __bf16* __restrict__ gk,
    float* __restrict__ sums) {
  int chunk = blockIdx.x, b = blockIdx.y, z = blockIdx.z;
  if (z == 0 && chunk >= 8) return;
  const __bf16* src = z ? gk : gq;
  int rows = z ? 2048 : 1024;
  const unsigned* base = (const unsigned*)(src + (size_t)b * rows * 64) + chunk * 128 * 32;
  int t = threadIdx.x, c = t & 31, ro = t >> 5;
  float s0 = 0.f, s1 = 0.f;
  for (int r = ro; r < 128; r += 8) {
    unsigned u = base[r * 32 + c];
    float f0 = __uint_as_float(u << 16);
    float f1 = __uint_as_float(u & 0xffff0000u);
    s0 += f0 * f0;
    s1 += f1 * f1;
  }
  __shared__ float ls[64];
  if (t < 64) ls[t] = 0.f;
  __syncthreads();
  atomicAdd(&ls[c * 2], s0);
  atomicAdd(&ls[c * 2 + 1], s1);
  __syncthreads();
  if (t < 64) atomicAdd(&sums[z * 256 + b * 64 + t], ls[t]);
}

// ---------------- l2 phase 2: scale geo_k by 1/(||q_p||*||k_p||) -----------
__global__ __launch_bounds__(256) void k_l2scale(
    __bf16* __restrict__ gk, const float* __restrict__ sums) {
  int chunk = blockIdx.x, b = blockIdx.y;
  unsigned* base = (unsigned*)(gk + (size_t)b * 2048 * 64) + chunk * 128 * 32;
  int t = threadIdx.x, c = t & 31, ro = t >> 5;
  float sq0 = sums[b * 64 + c * 2], sq1 = sums[b * 64 + c * 2 + 1];
  float sk0 = sums[256 + b * 64 + c * 2], sk1 = sums[256 + b * 64 + c * 2 + 1];
  float m0 = 1.f / (fmaxf(sqrtf(sq0), 1e-12f) * fmaxf(sqrtf(sk0), 1e-12f));
  float m1 = 1.f / (fmaxf(sqrtf(sq1), 1e-12f) * fmaxf(sqrtf(sk1), 1e-12f));
  for (int r = ro; r < 128; r += 8) {
    unsigned u = base[r * 32 + c];
    float f0 = __uint_as_float(u << 16) * m0;
    float f1 = __uint_as_float(u & 0xffff0000u) * m1;
    unsigned short h0 = __builtin_bit_cast(unsigned short, (__bf16)f0);
    unsigned short h1 = __builtin_bit_cast(unsigned short, (__bf16)f1);
    base[r * 32 + c] = (unsigned)h0 | ((unsigned)h1 << 16);
  }
}

// ---------------- fused QKV: qb(256) + kb(512) + vtb(512) blocks -----------
// m97 structure, 128x128 tile, K=1024. vtb part: A=Wv^T, Bt=kvin (operand
// swap -> writes V^T [ch][tok]) with row bias.
__global__ __launch_bounds__(256, 2) void k_qkv(
    const __bf16* __restrict__ qin, const __bf16* __restrict__ kvin,
    const __bf16* __restrict__ twq, const __bf16* __restrict__ twk,
    const __bf16* __restrict__ twv, const float* __restrict__ qbias,
    const float* __restrict__ kbias, const float* __restrict__ vbias,
    __bf16* __restrict__ qb, __bf16* __restrict__ kb, __bf16* __restrict__ vtb) {
  int id = blockIdx.x;
  const __bf16 *A, *Bt;
  const float* bias;
  __bf16* C;
  int my, nx, Ndim;
  bool rowbias;
  if (id < 256) {
    A = qin; Bt = twq; bias = qbias; C = qb;
    nx = id & 7; my = id >> 3; Ndim = 1024; rowbias = false;
  } else if (id < 768) {
    id -= 256;
    A = kvin; Bt = twk; bias = kbias; C = kb;
    nx = id & 7; my = id >> 3; Ndim = 1024; rowbias = false;
  } else {
    id -= 768;
    A = twv; Bt = kvin; bias = vbias; C = vtb;
    nx = id & 63; my = id >> 6; Ndim = 8192; rowbias = true;
  }
  const int Kdim = 1024;
  __shared__ __align__(16) __bf16 As[128 * 32];
  __shared__ __align__(16) __bf16 Bs[128 * 32];
  const int m0 = my * 128, n0 = nx * 128;
  const int t = threadIdx.x, lane = t & 63, w = t >> 6;
  const int quad = lane >> 4, l15 = lane & 15;
  const int wr = w >> 1, wc = w & 1;
  const int srow = lane >> 2, scol = (lane & 3) * 8;
  const __bf16* aS0 = A + (size_t)(m0 + w * 32 + srow) * Kdim + scol;
  const __bf16* bS0 = Bt + (size_t)(n0 + w * 32 + srow) * Kdim + scol;
  const size_t K16 = (size_t)16 * Kdim;
  __bf16* lA0 = &As[(w * 32) * 32];
  __bf16* lB0 = &Bs[(w * 32) * 32];

  f32x4 acc[4][4] = {};
  for (int k0 = 0; k0 < Kdim; k0 += 32) {
    __syncthreads();
    glds16(aS0 + k0, lA0);
    glds16(aS0 + K16 + k0, lA0 + 16 * 32);
    glds16(bS0 + k0, lB0);
    glds16(bS0 + K16 + k0, lB0 + 16 * 32);
    __syncthreads();
    bf16x8 af[4], bg[4];
#pragma unroll
    for (int rt = 0; rt < 4; rt++)
      af[rt] = *(const bf16x8*)&As[(wr * 64 + rt * 16 + l15) * 32 + quad * 8];
#pragma unroll
    for (int ct = 0; ct < 4; ct++)
      bg[ct] = *(const bf16x8*)&Bs[(wc * 64 + ct * 16 + l15) * 32 + quad * 8];
#pragma unroll
    for (int rt = 0; rt < 4; rt++)
#pragma unroll
      for (int ct = 0; ct < 4; ct++)
        acc[rt][ct] = mfma16(af[rt], bg[ct], acc[rt][ct]);
  }
#pragma unroll
  for (int rt = 0; rt < 4; rt++) {
    int row = m0 + wr * 64 + rt * 16 + quad * 4;
#pragma unroll
    for (int ct = 0; ct < 4; ct++) {
      int col = n0 + wc * 64 + ct * 16 + l15;
      float bcol = rowbias ? 0.f : bias[col];
#pragma unroll
      for (int i = 0; i < 4; i++) {
        float vv = acc[rt][ct][i] + (rowbias ? bias[row + i] : bcol);
        C[(size_t)(row + i) * Ndim + col] = (__bf16)vv;
      }
    }
  }
}

// ---------------- big GEMM: m97 structure (wo / ff1 / ff2) -----------------
// EPI: 2 = +bias(col) +residual -> f32 | 3 = +bias(col), exact gelu -> bf16
template <int EPI>
__global__ __launch_bounds__(256, 2) void k_gemm128(
    const __bf16* __restrict__ A, const __bf16* __restrict__ Bt,
    const float* __restrict__ bias, const float* __restrict__ resid,
    void* __restrict__ Cout, int Mdim, int Ndim, int Kdim) {
  __shared__ __align__(16) __bf16 As[128 * 32];
  __shared__ __align__(16) __bf16 Bs[128 * 32];
  const int m0 = blockIdx.y * 128, n0 = blockIdx.x * 128;
  const int t = threadIdx.x, lane = t & 63, w = t >> 6;
  const int quad = lane >> 4, l15 = lane & 15;
  const int wr = w >> 1, wc = w & 1;
  const int srow = lane >> 2, scol = (lane & 3) * 8;
  const __bf16* aS0 = A + (size_t)(m0 + w * 32 + srow) * Kdim + scol;
  const __bf16* bS0 = Bt + (size_t)(n0 + w * 32 + srow) * Kdim + scol;
  const size_t K16 = (size_t)16 * Kdim;
  __bf16* lA0 = &As[(w * 32) * 32];
  __bf16* lB0 = &Bs[(w * 32) * 32];

  f32x4 acc[4][4] = {};
  for (int k0 = 0; k0 < Kdim; k0 += 32) {
    __syncthreads();
    glds16(aS0 + k0, lA0);
    glds16(aS0 + K16 + k0, lA0 + 16 * 32);
    glds16(bS0 + k0, lB0);
    glds16(bS0 + K16 + k0, lB0 + 16 * 32);
    __syncthreads();
    bf16x8 af[4], bg[4];
#pragma unroll
    for (int rt = 0; rt < 4; rt++)
      af[rt] = *(const bf16x8*)&As[(wr * 64 + rt * 16 + l15) * 32 + quad * 8];
#pragma unroll
    for (int ct = 0; ct < 4; ct++)
      bg[ct] = *(const bf16x8*)&Bs[(wc * 64 + ct * 16 + l15) * 32 + quad * 8];
#pragma unroll
    for (int rt = 0; rt < 4; rt++)
#pragma unroll
      for (int ct = 0; ct < 4; ct++)
        acc[rt][ct] = mfma16(af[rt], bg[ct], acc[rt][ct]);
  }
#pragma unroll
  for (int rt = 0; rt < 4; rt++) {
    int row = m0 + wr * 64 + rt * 16 + quad * 4;
#pragma unroll
    for (int ct = 0; ct < 4; ct++) {
      int col = n0 + wc * 64 + ct * 16 + l15;
      float bcol = bias[col];
#pragma unroll
      for (int i = 0; i < 4; i++) {
        float vv = acc[rt][ct][i] + bcol;
        size_t idx = (size_t)(row + i) * Ndim + col;
        if (EPI == 2) {
          ((float*)Cout)[idx] = vv + resid[idx];
        } else {
          ((__bf16*)Cout)[idx] = (__bf16)(0.5f * vv * (1.f + erff(vv * 0.70710678118f)));
        }
      }
    }
  }
}

// ---------------- flash attention: LDS-staged K/Gk/V tiles -----------------
// Block = 128 Q-rows x (b,h); 4 waves x 32 rows. Per iter a 64-KV-col slab:
// K(64x64ch), Gk(64x64), V^T(64chx64tok) staged once into padded LDS and
// shared by all waves; next iter's slab prefetched into registers during
// compute (k_geo pipeline). No online max (logits bounded ~62). Block order
// (b,h)-major: o%64==bh so same-KV blocks share an XCD L2 (o%8 const).
__global__ __launch_bounds__(256, 2) void k_flash(
    const __bf16* __restrict__ Q, const __bf16* __restrict__ K,
    const __bf16* __restrict__ Vt, const __bf16* __restrict__ Gq,
    const __bf16* __restrict__ Gk, const float* __restrict__ als,
    const float* __restrict__ psc, const float* __restrict__ nsc,
    __bf16* __restrict__ Out) {
  const int o = blockIdx.x;
  const int bh = o & 63, x = o >> 6;
  const int b = bh & 3, h = bh >> 2;
  const int t = threadIdx.x, w = t >> 6, lane = t & 63;
  const int quad = lane >> 4, l15 = lane & 15;
  const int row0 = x * 128 + w * 32;
  const float sc = __expf(als[0]) * 0.125f;
  const float pos = psc[0], neg = nsc[0];

  __shared__ __align__(16) __bf16 Ks[64][72];
  __shared__ __align__(16) __bf16 Gs[64][72];
  __shared__ __align__(16) __bf16 Vs[64][72];
  __shared__ __align__(16) __bf16 plds[4][32][72];

  const __bf16* Qb = Q + ((size_t)(b * NN + row0)) * DB + h * DHD;
  const __bf16* Kb = K + ((size_t)b * NM) * DB + h * DHD;
  const __bf16* Vb = Vt + (size_t)(h * DHD) * (NB * NM) + (size_t)b * NM;
  const __bf16* Gqb = Gq + (size_t)(b * NN + row0) * DP;
  const __bf16* Gkb = Gk + (size_t)b * NM * DP;

  // staging: thread t covers chunk rows r0 and r0+32, 16B col c0
  const int r0 = t >> 3, c0 = (t & 7) * 8;
  const int r1 = r0 + 32;

  bf16x8 qf[2][2], gqf[2][2];
#pragma unroll
  for (int rt = 0; rt < 2; rt++)
#pragma unroll
    for (int ks = 0; ks < 2; ks++) {
      qf[rt][ks] = *(const bf16x8*)(Qb + (size_t)(rt * 16 + l15) * DB + ks * 32 + quad * 8);
      gqf[rt][ks] = *(const bf16x8*)(Gqb + (size_t)(rt * 16 + l15) * DP + ks * 32 + quad * 8);
    }

  // prefetch first slab
  bf16x8 kst0 = *(const bf16x8*)(Kb + (size_t)r0 * DB + c0);
  bf16x8 kst1 = *(const bf16x8*)(Kb + (size_t)r1 * DB + c0);
  bf16x8 gst0 = *(const bf16x8*)(Gkb + (size_t)r0 * DP + c0);
  bf16x8 gst1 = *(const bf16x8*)(Gkb + (size_t)r1 * DP + c0);
  bf16x8 vst0 = *(const bf16x8*)(Vb + (size_t)r0 * (NB * NM) + c0);
  bf16x8 vst1 = *(const bf16x8*)(Vb + (size_t)r1 * (NB * NM) + c0);

  float lrow[2][4] = {};
  f32x4 oacc[2][4] = {};
  f32x4 z4 = {0.f, 0.f, 0.f, 0.f};

  for (int m0 = 0; m0 < NM; m0 += 64) {
    __syncthreads();  // prior iter's tile reads complete
    *(bf16x8*)&Ks[r0][c0] = kst0;
    *(bf16x8*)&Ks[r1][c0] = kst1;
    *(bf16x8*)&Gs[r0][c0] = gst0;
    *(bf16x8*)&Gs[r1][c0] = gst1;
    *(bf16x8*)&Vs[r0][c0] = vst0;
    *(bf16x8*)&Vs[r1][c0] = vst1;
    __syncthreads();  // tiles visible to all waves
    if (m0 + 64 < NM) {  // prefetch next slab (latency hidden by compute)
      kst0 = *(const bf16x8*)(Kb + (size_t)(m0 + 64 + r0) * DB + c0);
      kst1 = *(const bf16x8*)(Kb + (size_t)(m0 + 64 + r1) * DB + c0);
      gst0 = *(const bf16x8*)(Gkb + (size_t)(m0 + 64 + r0) * DP + c0);
      gst1 = *(const bf16x8*)(Gkb + (size_t)(m0 + 64 + r1) * DP + c0);
      vst0 = *(const bf16x8*)(Vb + (size_t)r0 * (NB * NM) + m0 + 64 + c0);
      vst1 = *(const bf16x8*)(Vb + (size_t)r1 * (NB * NM) + m0 + 64 + c0);
    }
    bf16x8 kf[4][2], gkf[4][2];
#pragma unroll
    for (int ct = 0; ct < 4; ct++)
#pragma unroll
      for (int ks = 0; ks < 2; ks++) {
        kf[ct][ks] = *(const bf16x8*)&Ks[ct * 16 + l15][ks * 32 + quad * 8];
        gkf[ct][ks] = *(const bf16x8*)&Gs[ct * 16 + l15][ks * 32 + quad * 8];
      }
#pragma unroll
    for (int rt = 0; rt < 2; rt++)
#pragma unroll
      for (int ct = 0; ct < 4; ct++) {
        f32x4 s = mfma16(qf[rt][1], kf[ct][1], mfma16(qf[rt][0], kf[ct][0], z4));
        f32x4 bg = mfma16(gqf[rt][1], gkf[ct][1], mfma16(gqf[rt][0], gkf[ct][0], z4));
#pragma unroll
        for (int i = 0; i < 4; i++) {
          float bb = bg[i];
          float fb = bb > 0.f ? bb * pos : bb * neg;
          float p = __expf(s[i] * sc + fb);
          lrow[rt][i] += p;
          plds[w][rt * 16 + quad * 4 + i][ct * 16 + l15] = (__bf16)p;
        }
      }
    // P (C-layout) -> per-wave LDS -> A-frags; V frags from shared tile
    bf16x8 pf[2][2], vf[4][2];
#pragma unroll
    for (int rt = 0; rt < 2; rt++)
#pragma unroll
      for (int ms = 0; ms < 2; ms++)
        pf[rt][ms] = *(const bf16x8*)&plds[w][rt * 16 + l15][ms * 32 + quad * 8];
#pragma unroll
    for (int dt = 0; dt < 4; dt++)
#pragma unroll
      for (int ms = 0; ms < 2; ms++)
        vf[dt][ms] = *(const bf16x8*)&Vs[dt * 16 + l15][ms * 32 + quad * 8];
#pragma unroll
    for (int rt = 0; rt < 2; rt++)
#pragma unroll
      for (int dt = 0; dt < 4; dt++) {
        oacc[rt][dt] = mfma16(pf[rt][0], vf[dt][0], oacc[rt][dt]);
        oacc[rt][dt] = mfma16(pf[rt][1], vf[dt][1], oacc[rt][dt]);
      }
  }
  // final l reduction over the 16 column-lanes (same quad), then store
#pragma unroll
  for (int rt = 0; rt < 2; rt++)
#pragma unroll
    for (int i = 0; i < 4; i++) {
      float l = lrow[rt][i];
#pragma unroll
      for (int o2 = 1; o2 < 16; o2 <<= 1) l += __shfl_xor(l, o2, 64);
      float inv = 1.f / l;
#pragma unroll
      for (int dt = 0; dt < 4; dt++)
        Out[(size_t)(b * NN + row0 + rt * 16 + quad * 4 + i) * DB + h * DHD + dt * 16 + l15] =
            (__bf16)(oacc[rt][dt][i] * inv);
    }
}

// ---------------------------------------------------------------------------
extern "C" void kernel_launch(void* const* d_in, const int* in_sizes, int n_in,
                              void* d_out, int out_size, void* d_ws, size_t ws_size,
                              hipStream_t stream) {
  const float* dataset = (const float*)d_in[0];
  const float* visual = (const float*)d_in[1];
  const float* wq_w = (const float*)d_in[2];
  const float* wq_b = (const float*)d_in[3];
  const float* wk_w = (const float*)d_in[4];
  const float* wk_b = (const float*)d_in[5];
  const float* wv_w = (const float*)d_in[6];
  const float* wv_b = (const float*)d_in[7];
  const float* wo_w = (const float*)d_in[8];
  const float* wo_b = (const float*)d_in[9];
  const float* gq_w = (const float*)d_in[10];
  const float* gq_b = (const float*)d_in[11];
  const float* gk_w = (const float*)d_in[12];
  const float* gk_b = (const float*)d_in[13];
  const float* pos_scale = (const float*)d_in[14];
  const float* neg_scale = (const float*)d_in[15];
  const float* als = (const float*)d_in[16];
  const float* ln_q_g = (const float*)d_in[17];
  const float* ln_q_b = (const float*)d_in[18];
  const float* ln_kv_g = (const float*)d_in[19];
  const float* ln_kv_b = (const float*)d_in[20];
  const float* ln_out_g = (const float*)d_in[21];
  const float* ln_out_b = (const float*)d_in[22];
  const float* ff1_w = (const float*)d_in[23];
  const float* ff1_b = (const float*)d_in[24];
  const float* ff2_w = (const float*)d_in[25];
  const float* ff2_b = (const float*)d_in[26];

  char* ws = (char*)d_ws;
  size_t off = 0;
  auto alloc = [&](size_t bytes) {
    size_t o = off;
    off += (bytes + 255) & ~(size_t)255;
    return o;
  };
  __bf16* t_wq = (__bf16*)(ws + alloc((size_t)1024 * 1024 * 2));
  __bf16* t_wk = (__bf16*)(ws + alloc((size_t)1024 * 1024 * 2));
  __bf16* t_wv = (__bf16*)(ws + alloc((size_t)1024 * 1024 * 2));
  __bf16* t_wo = (__bf16*)(ws + alloc((size_t)1024 * 1024 * 2));
  __bf16* t_ff1 = (__bf16*)(ws + alloc((size_t)2048 * 1024 * 2));
  __bf16* t_ff2 = (__bf16*)(ws + alloc((size_t)1024 * 2048 * 2));
  __bf16* t_gq = (__bf16*)(ws + alloc((size_t)64 * 1024 * 2));
  __bf16* t_gk = (__bf16*)(ws + alloc((size_t)64 * 1024 * 2));
  size_t qin_off = alloc((size_t)4096 * 1024 * 2);   // aliased as hbuf later
  size_t kvin_off = alloc((size_t)8192 * 1024 * 2);  // aliased as out1(f32) later
  __bf16* qin = (__bf16*)(ws + qin_off);
  __bf16* kvin = (__bf16*)(ws + kvin_off);
  __bf16* geoq = (__bf16*)(ws + alloc((size_t)4096 * 64 * 2));
  __bf16* geok = (__bf16*)(ws + alloc((size_t)8192 * 64 * 2));
  float* sums = (float*)(ws + alloc((size_t)2 * 4 * 64 * 4));
  __bf16* qb = (__bf16*)(ws + alloc((size_t)4096 * 1024 * 2));
  __bf16* kb = (__bf16*)(ws + alloc((size_t)8192 * 1024 * 2));
  __bf16* vtb = (__bf16*)(ws + alloc((size_t)1024 * 8192 * 2));  // V^T [ch][tok]
  __bf16* attn = (__bf16*)(ws + alloc((size_t)4096 * 1024 * 2));
  __bf16* ffh = (__bf16*)(ws + alloc((size_t)4096 * 2048 * 2));
  // aliases (lifetimes disjoint):
  float* out1 = (float*)(ws + kvin_off);   // f32 [4096,1024] over kv_in
  __bf16* hbuf = (__bf16*)(ws + qin_off);  // bf16 [4096,1024] over q_in
  float* outp = (float*)d_out;

  dim3 blk(256);
  // 1. all weight transposes in one launch
  k_transpose_all<<<8320, blk, 0, stream>>>(wq_w, wk_w, wv_w, wo_w, ff1_w, ff2_w,
                                            gq_w, gk_w, t_wq, t_wk, t_wv, t_wo,
                                            t_ff1, t_ff2, t_gq, t_gk);
  // 2. both input layernorms in one launch
  k_layernorm2<<<12288, blk, 0, stream>>>(dataset, ln_q_g, ln_q_b, qin,
                                          visual, ln_kv_g, ln_kv_b, kvin);
  // 3. geo path
  k_geo<<<384, blk, 0, stream>>>(qin, kvin, t_gq, t_gk, gq_b, gk_b, geoq, geok);
  hipMemsetAsync(sums, 0, 2 * 4 * 64 * 4, stream);
  k_l2sum<<<dim3(16, 4, 2), blk, 0, stream>>>(geoq, geok, sums);
  k_l2scale<<<dim3(16, 4), blk, 0, stream>>>(geok, sums);
  // 4. fused QKV projections (qb | kb | vtb in one 1280-block launch)
  k_qkv<<<1280, blk, 0, stream>>>(qin, kvin, t_wq, t_wk, t_wv,
                                  wq_b, wk_b, wv_b, qb, kb, vtb);
  // 5. flash attention (bias fused, LDS-staged shared tiles)
  k_flash<<<512, blk, 0, stream>>>(qb, kb, vtb, geoq, geok, als,
                                   pos_scale, neg_scale, attn);
  // 6. output projection + residual, LN, FFN
  k_gemm128<2><<<dim3(8, 32), blk, 0, stream>>>(attn, t_wo, wo_b, dataset, out1,
                                                4096, 1024, 1024);
  k_layernorm<<<4096, blk, 0, stream>>>(out1, ln_out_g, ln_out_b, hbuf);
  k_gemm128<3><<<dim3(16, 32), blk, 0, stream>>>(hbuf, t_ff1, ff1_b, nullptr, ffh,
                                                 4096, 2048, 1024);
  k_gemm128<2><<<dim3(8, 32), blk, 0, stream>>>(ffh, t_ff2, ff2_b, out1, outp,
                                                4096, 1024, 2048);
}